// Round 3
// baseline (219.638 us; speedup 1.0000x reference)
//
#include <hip/hip_runtime.h>
#include <math.h>

// Problem constants: E=3, B=4096, D=1024, M=5, N=256
// loss = mean(sum(feature*gt,-1)) + 0.1 * (sum_e OT_e * 2) / E
typedef float f32x4 __attribute__((ext_vector_type(4)));

#define NSIM_BLOCKS 48            // 3 e * 16 chunks of 16 rows
#define NDOT_BLOCKS 2000
#define NBLOCKS (NSIM_BLOCKS + NDOT_BLOCKS)   // 2048 = 8 blocks/CU exactly
#define THREADS 256
#define TOTAL_F4 3145728          // 3*4096*1024 / 4
#define DOT_STRIDE (NDOT_BLOCKS * THREADS)    // 512000

// ws layout (floats): [0,2000) dot partials | [2048,5888) sim | int counter @6144
#define WS_SIM_OFF 2048
#define WS_CTR_OFF 6144

// Single fused kernel. Blocks [0,48): normalized sim[e][m][n] -> ws_sim.
// Blocks [48,2048): streaming feature.gt partials -> ws_partials.
// Last block to finish (atomic counter) runs Sinkhorn + final combine.
// LDS = exactly 20480 B so 8 blocks/CU co-reside (32 waves/CU).
__global__ __launch_bounds__(256) void fused_all(
    const f32x4* __restrict__ f4, const f32x4* __restrict__ g4,
    const float* __restrict__ gt_local, const float* __restrict__ feat_local,
    float* __restrict__ ws, float* __restrict__ out)
{
    __shared__ float s_sh[5120];   // 20 KB exactly; scratch aliased below
    float* red_sh = s_sh;                  // [0..3] dot cross-wave reduce
    int* flag_sh = (int*)&s_sh[8];         // last-block flag
    float* ot_sh = &s_sh[12];              // [12..14] per-e OT results
    double* g_sh = (double*)&s_sh[16];     // 8B-aligned global-dot sum

    float* ws_partials = ws;
    float* ws_sim = ws + WS_SIM_OFF;
    unsigned int* counter = (unsigned int*)(ws + WS_CTR_OFF);

    const int tid = threadIdx.x;
    const int lane = tid & 63;
    const int wid = tid >> 6;

    if (blockIdx.x >= NSIM_BLOCKS) {
        // ---- streaming dot-product blocks (LLC-warm inputs: no nt loads) ----
        const int base = (blockIdx.x - NSIM_BLOCKS) * THREADS + tid;
        f32x4 p = {0.f, 0.f, 0.f, 0.f};
        #pragma unroll
        for (int k = 0; k < 6; ++k) {
            const f32x4 a = f4[base + k * DOT_STRIDE];
            const f32x4 b = g4[base + k * DOT_STRIDE];
            p += a * b;
        }
        if (base + 6 * DOT_STRIDE < TOTAL_F4) {
            const f32x4 a = f4[base + 6 * DOT_STRIDE];
            const f32x4 b = g4[base + 6 * DOT_STRIDE];
            p += a * b;
        }
        float acc = p.x + p.y + p.z + p.w;
        #pragma unroll
        for (int o = 32; o; o >>= 1) acc += __shfl_xor(acc, o);
        if (lane == 0) red_sh[wid] = acc;
        __syncthreads();
        if (tid == 0)
            ws_partials[blockIdx.x - NSIM_BLOCKS] =
                red_sh[0] + red_sh[1] + red_sh[2] + red_sh[3];
    } else {
        // ---- similarity blocks ----
        const int e = blockIdx.x >> 4;     // 0..2
        const int chunk = blockIdx.x & 15; // 0..15 (16 n-rows each)
        const f32x4* sbase = (const f32x4*)(gt_local + e * 5120);
        #pragma unroll
        for (int k = 0; k < 5; ++k)
            ((f32x4*)s_sh)[tid + 256 * k] = sbase[tid + 256 * k];
        __syncthreads();
        // row norms of s; scale rows in place (same wave scales its own row)
        for (int m = wid; m < 5; m += 4) {
            float acc = 0.f;
            #pragma unroll
            for (int k = 0; k < 16; ++k) {
                float v = s_sh[m * 1024 + lane + 64 * k];
                acc += v * v;
            }
            #pragma unroll
            for (int o = 32; o; o >>= 1) acc += __shfl_xor(acc, o);
            const float rinv = 1.f / fmaxf(sqrtf(acc), 1e-12f);
            #pragma unroll
            for (int k = 0; k < 16; ++k)
                s_sh[m * 1024 + lane + 64 * k] *= rinv;
        }
        __syncthreads();
        // wave-per-t-row: 4 waves * 4 rows = 16 rows per block
        for (int rr = 0; rr < 4; ++rr) {
            const int n = chunk * 16 + wid * 4 + rr;
            const float* trow = feat_local + (e * 256 + n) * 1024;
            float a0 = 0.f, a1 = 0.f, a2 = 0.f, a3 = 0.f, a4 = 0.f, at = 0.f;
            #pragma unroll
            for (int k = 0; k < 16; ++k) {
                const int d = lane + 64 * k;          // coalesced per wave
                const float tv = trow[d];
                at += tv * tv;
                a0 += tv * s_sh[d];
                a1 += tv * s_sh[1024 + d];
                a2 += tv * s_sh[2048 + d];
                a3 += tv * s_sh[3072 + d];
                a4 += tv * s_sh[4096 + d];
            }
            #pragma unroll
            for (int o = 32; o; o >>= 1) {
                at += __shfl_xor(at, o);
                a0 += __shfl_xor(a0, o);
                a1 += __shfl_xor(a1, o);
                a2 += __shfl_xor(a2, o);
                a3 += __shfl_xor(a3, o);
                a4 += __shfl_xor(a4, o);
            }
            if (lane == 0) {
                const float rnt = 1.f / fmaxf(sqrtf(at), 1e-12f);
                float* dst = ws_sim + e * 5 * 256 + n;
                dst[0]    = a0 * rnt;
                dst[256]  = a1 * rnt;
                dst[512]  = a2 * rnt;
                dst[768]  = a3 * rnt;
                dst[1024] = a4 * rnt;
            }
        }
        __syncthreads();
    }

    // ---- last-block-done election (device-scope fence + atomic counter) ----
    if (tid == 0) {
        __threadfence();                       // release our block's stores
        flag_sh[0] = (atomicAdd(counter, 1u) == NBLOCKS - 1);
    }
    __syncthreads();
    if (!flag_sh[0]) return;

    // ---- finalize (runs in exactly one block, after all stores visible) ----
    __threadfence();                           // acquire
    __syncthreads();

    if (wid < 3) {
        // Sinkhorn per extractor: lane owns 4 columns of the 5x256 K matrix
        const int e = wid;
        float K[5][4], S[5][4];
        #pragma unroll
        for (int m = 0; m < 5; ++m)
            #pragma unroll
            for (int j = 0; j < 4; ++j) {
                const float s = ws_sim[(e * 5 + m) * 256 + lane + 64 * j];
                S[m][j] = s;
                K[m][j] = expf(-(1.0f - s) / 0.1f);   // SINK_EPS = 0.1
            }
        float r[5] = {1.f, 1.f, 1.f, 1.f, 1.f};
        float c[4] = {1.f, 1.f, 1.f, 1.f};
        float err;
        int it = 0;
        do {
            float r0[5];
            #pragma unroll
            for (int m = 0; m < 5; ++m) r0[m] = r[m];
            #pragma unroll
            for (int m = 0; m < 5; ++m) {
                float p = K[m][0] * c[0] + K[m][1] * c[1] +
                          K[m][2] * c[2] + K[m][3] * c[3];
                #pragma unroll
                for (int o = 32; o; o >>= 1) p += __shfl_xor(p, o);
                r[m] = 0.2f / p;                      // u = 1/M = 1/5
            }
            #pragma unroll
            for (int j = 0; j < 4; ++j) {
                const float q = K[0][j] * r[0] + K[1][j] * r[1] +
                                K[2][j] * r[2] + K[3][j] * r[3] +
                                K[4][j] * r[4];
                c[j] = (1.0f / 256.0f) / q;           // v = 1/N
            }
            err = (fabsf(r[0] - r0[0]) + fabsf(r[1] - r0[1]) +
                   fabsf(r[2] - r0[2]) + fabsf(r[3] - r0[3]) +
                   fabsf(r[4] - r0[4])) * 0.2f;       // mean over M=5
            ++it;
        } while (it < 100 && err >= 0.01f);           // MAX_ITERS, THRESH

        float ot = 0.f;
        #pragma unroll
        for (int m = 0; m < 5; ++m)
            #pragma unroll
            for (int j = 0; j < 4; ++j)
                ot += r[m] * c[j] * K[m][j] * S[m][j];
        #pragma unroll
        for (int o = 32; o; o >>= 1) ot += __shfl_xor(ot, o);
        if (lane == 0) ot_sh[e] = ot;
    } else if (wid == 3) {
        // reduce 2000 dot partials in double
        double acc = 0.0;
        #pragma unroll
        for (int k = 0; k < 32; ++k) {
            const int idx = lane + 64 * k;
            if (idx < NDOT_BLOCKS) acc += (double)ws_partials[idx];
        }
        #pragma unroll
        for (int o = 32; o; o >>= 1) acc += __shfl_xor(acc, o);
        if (lane == 0) g_sh[0] = acc;
    }
    __syncthreads();
    if (tid == 0) {
        const float loss_global = (float)(g_sh[0] / 12288.0);   // mean over E*B
        const float loss_local = (ot_sh[0] + ot_sh[1] + ot_sh[2]) * 2.0f / 3.0f;
        out[0] = loss_global + 0.1f * loss_local;
    }
}

extern "C" void kernel_launch(void* const* d_in, const int* in_sizes, int n_in,
                              void* d_out, int out_size, void* d_ws, size_t ws_size,
                              hipStream_t stream) {
    const f32x4* f4 = (const f32x4*)d_in[0];            // feature  [3,4096,1024]
    const f32x4* g4 = (const f32x4*)d_in[1];            // gt       [3,4096,1024]
    const float* gt_local = (const float*)d_in[2];      // [3,5,1024]
    const float* feat_local = (const float*)d_in[3];    // [3,256,1024]
    float* ws = (float*)d_ws;
    float* out = (float*)d_out;

    // zero the last-block counter (ws is poisoned 0xAA before every launch)
    hipMemsetAsync((char*)d_ws + WS_CTR_OFF * sizeof(float), 0,
                   sizeof(unsigned int), stream);
    hipLaunchKernelGGL(fused_all, dim3(NBLOCKS), dim3(THREADS), 0, stream,
                       f4, g4, gt_local, feat_local, ws, out);
}

// Round 4
// 127.559 us; speedup vs baseline: 1.7218x; 1.7218x over previous
//
#include <hip/hip_runtime.h>
#include <math.h>

// Problem constants: E=3, B=4096, D=1024, M=5, N=256
// loss = mean(sum(feature*gt,-1)) + 0.1 * (sum_e OT_e * 2) / E
typedef float f32x4 __attribute__((ext_vector_type(4)));

#define NSIM_BLOCKS 48            // 3 e * 16 chunks of 16 rows
#define NDOT_BLOCKS 2048          // 8 blocks/CU; 2048*256*6 == TOTAL_F4 exactly
#define THREADS 256
#define TOTAL_F4 3145728          // 3*4096*1024 / 4
#define DOT_STRIDE (NDOT_BLOCKS * THREADS)    // 524288

// Kernel 1: blocks [0,2048) stream feature.gt partials into ws_partials;
//           blocks [2048,2096) compute normalized sim[e][m][n] into ws_sim.
// No device fences / atomics anywhere (R3 showed per-block agent-scope
// release costs ~100us on 8-XCD gfx950). LDS = 20480 B -> 8 blocks/CU.
__global__ __launch_bounds__(256) void fused_main(
    const f32x4* __restrict__ f4, const f32x4* __restrict__ g4,
    const float* __restrict__ gt_local, const float* __restrict__ feat_local,
    float* __restrict__ ws_partials, float* __restrict__ ws_sim)
{
    __shared__ float s_sh[5120];   // 20 KB exactly; dot path aliases [0..3]
    const int tid = threadIdx.x;
    const int lane = tid & 63;
    const int wid = tid >> 6;

    if (blockIdx.x < NDOT_BLOCKS) {
        // ---- streaming dot-product blocks (plain loads: inputs LLC-warm) ----
        const int base = blockIdx.x * THREADS + tid;
        // 6 independent f4-pairs, fully unrolled -> 12 loads in flight/lane
        const f32x4 a0 = f4[base + 0 * DOT_STRIDE];
        const f32x4 b0 = g4[base + 0 * DOT_STRIDE];
        const f32x4 a1 = f4[base + 1 * DOT_STRIDE];
        const f32x4 b1 = g4[base + 1 * DOT_STRIDE];
        const f32x4 a2 = f4[base + 2 * DOT_STRIDE];
        const f32x4 b2 = g4[base + 2 * DOT_STRIDE];
        const f32x4 a3 = f4[base + 3 * DOT_STRIDE];
        const f32x4 b3 = g4[base + 3 * DOT_STRIDE];
        const f32x4 a4 = f4[base + 4 * DOT_STRIDE];
        const f32x4 b4 = g4[base + 4 * DOT_STRIDE];
        const f32x4 a5 = f4[base + 5 * DOT_STRIDE];
        const f32x4 b5 = g4[base + 5 * DOT_STRIDE];
        f32x4 p0 = a0 * b0 + a1 * b1;
        f32x4 p1 = a2 * b2 + a3 * b3;
        f32x4 p2 = a4 * b4 + a5 * b5;
        f32x4 p = p0 + p1 + p2;
        float acc = p.x + p.y + p.z + p.w;
        #pragma unroll
        for (int o = 32; o; o >>= 1) acc += __shfl_xor(acc, o);
        if (lane == 0) s_sh[wid] = acc;
        __syncthreads();
        if (tid == 0)
            ws_partials[blockIdx.x] = s_sh[0] + s_sh[1] + s_sh[2] + s_sh[3];
    } else {
        // ---- similarity blocks ----
        const int b = blockIdx.x - NDOT_BLOCKS;
        const int e = b >> 4;              // 0..2
        const int chunk = b & 15;          // 0..15 (16 n-rows each)
        const f32x4* sbase = (const f32x4*)(gt_local + e * 5120);
        #pragma unroll
        for (int k = 0; k < 5; ++k)
            ((f32x4*)s_sh)[tid + 256 * k] = sbase[tid + 256 * k];
        __syncthreads();
        // row norms of s; scale rows in place (same wave scales its own row)
        for (int m = wid; m < 5; m += 4) {
            float acc = 0.f;
            #pragma unroll
            for (int k = 0; k < 16; ++k) {
                float v = s_sh[m * 1024 + lane + 64 * k];
                acc += v * v;
            }
            #pragma unroll
            for (int o = 32; o; o >>= 1) acc += __shfl_xor(acc, o);
            const float rinv = 1.f / fmaxf(sqrtf(acc), 1e-12f);
            #pragma unroll
            for (int k = 0; k < 16; ++k)
                s_sh[m * 1024 + lane + 64 * k] *= rinv;
        }
        __syncthreads();
        // wave-per-t-row: 4 waves * 4 rows = 16 rows per block
        for (int rr = 0; rr < 4; ++rr) {
            const int n = chunk * 16 + wid * 4 + rr;
            const float* trow = feat_local + (e * 256 + n) * 1024;
            float a0 = 0.f, a1 = 0.f, a2 = 0.f, a3 = 0.f, a4 = 0.f, at = 0.f;
            #pragma unroll
            for (int k = 0; k < 16; ++k) {
                const int d = lane + 64 * k;          // coalesced per wave
                const float tv = trow[d];
                at += tv * tv;
                a0 += tv * s_sh[d];
                a1 += tv * s_sh[1024 + d];
                a2 += tv * s_sh[2048 + d];
                a3 += tv * s_sh[3072 + d];
                a4 += tv * s_sh[4096 + d];
            }
            #pragma unroll
            for (int o = 32; o; o >>= 1) {
                at += __shfl_xor(at, o);
                a0 += __shfl_xor(a0, o);
                a1 += __shfl_xor(a1, o);
                a2 += __shfl_xor(a2, o);
                a3 += __shfl_xor(a3, o);
                a4 += __shfl_xor(a4, o);
            }
            if (lane == 0) {
                const float rnt = 1.f / fmaxf(sqrtf(at), 1e-12f);
                float* dst = ws_sim + e * 5 * 256 + n;
                dst[0]    = a0 * rnt;
                dst[256]  = a1 * rnt;
                dst[512]  = a2 * rnt;
                dst[768]  = a3 * rnt;
                dst[1024] = a4 * rnt;
            }
        }
    }
}

// Kernel 2: waves 0..2 run Sinkhorn per extractor (lane owns 4 columns of the
// 5x256 K matrix; all reductions are 64-lane butterflies). Wave 3 reduces the
// 2048 dot partials in double. Thread 0 combines.
__global__ __launch_bounds__(256) void finalize_kernel(
    const float* __restrict__ ws_partials, const float* __restrict__ ws_sim,
    float* __restrict__ out)
{
    __shared__ float ot_sh[3];
    __shared__ double g_sh;
    const int tid = threadIdx.x;
    const int lane = tid & 63;
    const int wid = tid >> 6;

    if (wid < 3) {
        const int e = wid;
        float K[5][4], S[5][4];
        #pragma unroll
        for (int m = 0; m < 5; ++m)
            #pragma unroll
            for (int j = 0; j < 4; ++j) {
                const float s = ws_sim[(e * 5 + m) * 256 + lane + 64 * j];
                S[m][j] = s;
                K[m][j] = expf(-(1.0f - s) / 0.1f);   // SINK_EPS = 0.1
            }
        float r[5] = {1.f, 1.f, 1.f, 1.f, 1.f};
        float c[4] = {1.f, 1.f, 1.f, 1.f};
        float err;
        int it = 0;
        do {
            float r0[5];
            #pragma unroll
            for (int m = 0; m < 5; ++m) r0[m] = r[m];
            #pragma unroll
            for (int m = 0; m < 5; ++m) {
                float p = K[m][0] * c[0] + K[m][1] * c[1] +
                          K[m][2] * c[2] + K[m][3] * c[3];
                #pragma unroll
                for (int o = 32; o; o >>= 1) p += __shfl_xor(p, o);
                r[m] = 0.2f / p;                      // u = 1/M = 1/5
            }
            #pragma unroll
            for (int j = 0; j < 4; ++j) {
                const float q = K[0][j] * r[0] + K[1][j] * r[1] +
                                K[2][j] * r[2] + K[3][j] * r[3] +
                                K[4][j] * r[4];
                c[j] = (1.0f / 256.0f) / q;           // v = 1/N
            }
            err = (fabsf(r[0] - r0[0]) + fabsf(r[1] - r0[1]) +
                   fabsf(r[2] - r0[2]) + fabsf(r[3] - r0[3]) +
                   fabsf(r[4] - r0[4])) * 0.2f;       // mean over M=5
            ++it;
        } while (it < 100 && err >= 0.01f);           // MAX_ITERS, THRESH

        float ot = 0.f;
        #pragma unroll
        for (int m = 0; m < 5; ++m)
            #pragma unroll
            for (int j = 0; j < 4; ++j)
                ot += r[m] * c[j] * K[m][j] * S[m][j];
        #pragma unroll
        for (int o = 32; o; o >>= 1) ot += __shfl_xor(ot, o);
        if (lane == 0) ot_sh[e] = ot;
    } else {
        // reduce 2048 dot partials in double
        double acc = 0.0;
        #pragma unroll
        for (int k = 0; k < 32; ++k) acc += (double)ws_partials[lane + 64 * k];
        #pragma unroll
        for (int o = 32; o; o >>= 1) acc += __shfl_xor(acc, o);
        if (lane == 0) g_sh = acc;
    }
    __syncthreads();
    if (tid == 0) {
        const float loss_global = (float)(g_sh / 12288.0);   // mean over E*B
        const float loss_local = (ot_sh[0] + ot_sh[1] + ot_sh[2]) * 2.0f / 3.0f;
        out[0] = loss_global + 0.1f * loss_local;
    }
}

extern "C" void kernel_launch(void* const* d_in, const int* in_sizes, int n_in,
                              void* d_out, int out_size, void* d_ws, size_t ws_size,
                              hipStream_t stream) {
    const f32x4* f4 = (const f32x4*)d_in[0];            // feature  [3,4096,1024]
    const f32x4* g4 = (const f32x4*)d_in[1];            // gt       [3,4096,1024]
    const float* gt_local = (const float*)d_in[2];      // [3,5,1024]
    const float* feat_local = (const float*)d_in[3];    // [3,256,1024]
    float* ws_partials = (float*)d_ws;                  // 2048 floats
    float* ws_sim = ws_partials + NDOT_BLOCKS;          // 3*5*256 floats
    float* out = (float*)d_out;

    hipLaunchKernelGGL(fused_main, dim3(NDOT_BLOCKS + NSIM_BLOCKS), dim3(THREADS),
                       0, stream, f4, g4, gt_local, feat_local, ws_partials, ws_sim);
    hipLaunchKernelGGL(finalize_kernel, dim3(1), dim3(THREADS), 0, stream,
                       ws_partials, ws_sim, out);
}